// Round 2
// 1047.753 us; speedup vs baseline: 1.1311x; 1.1311x over previous
//
#include <hip/hip_runtime.h>
#include <stdint.h>

#define B_  2
#define T_  2048
#define D_  1024
#define H_  4
#define S_  64
#define W_  512
#define CK_ 256
#define NC_ 32      // T_/64 chunks
#define BT_ 4096

typedef __attribute__((ext_vector_type(8))) short bf16x8;
typedef __attribute__((ext_vector_type(4))) float f32x4;

__device__ __forceinline__ float bf2f(unsigned short u){ return __uint_as_float(((unsigned int)u)<<16); }
__device__ __forceinline__ unsigned short f2bf(float f){
  unsigned int u = __float_as_uint(f);
  u += 0x7fffu + ((u>>16)&1u);
  return (unsigned short)(u>>16);
}

// ---------------- RMSNorm: x(B*T,D) -> out(B*T,D) fp32 ----------------
__global__ void rmsnorm_kernel(const float* __restrict__ x, const float* __restrict__ w,
                               float* __restrict__ out){
  int row = blockIdx.x, tid = threadIdx.x;
  const float* xr = x + (size_t)row*D_;
  float v0=xr[tid], v1=xr[tid+256], v2=xr[tid+512], v3=xr[tid+768];
  __shared__ float red[256];
  red[tid] = v0*v0+v1*v1+v2*v2+v3*v3;
  __syncthreads();
  for(int s=128;s>0;s>>=1){ if(tid<s) red[tid]+=red[tid+s]; __syncthreads(); }
  float r = rsqrtf(red[0]/(float)D_ + 1e-5f);
  float* orow = out + (size_t)row*D_;
  orow[tid]     = v0*r*w[tid];
  orow[tid+256] = v1*r*w[tid+256];
  orow[tid+512] = v2*r*w[tid+512];
  orow[tid+768] = v3*r*w[tid+768];
}

// ---------------- GEMM-NT: C[M,N] = A[M,K] * Wt[N,K]^T ----------------
__global__ __launch_bounds__(256) void gemm_nt(const float* __restrict__ A, const float* __restrict__ Wt,
                     float* __restrict__ Cf, unsigned short* __restrict__ Cbf,
                     unsigned short* __restrict__ CbfT,
                     int M, int N, int K){
  __shared__ float As[16][68];
  __shared__ float Bs[16][68];
  int tid = threadIdx.x;
  int tx = tid & 15, ty = tid >> 4;
  int row0 = blockIdx.y*64, col0 = blockIdx.x*64;
  int kq = tid & 15;
  int mq = tid >> 4;
  float acc[4][4] = {};
  for(int kt=0; kt<K; kt+=16){
    #pragma unroll
    for(int r=0;r<4;r++){
      As[kq][mq + r*16] = A [(size_t)(row0 + mq + r*16)*K + kt + kq];
      Bs[kq][mq + r*16] = Wt[(size_t)(col0 + mq + r*16)*K + kt + kq];
    }
    __syncthreads();
    #pragma unroll
    for(int kk=0;kk<16;kk++){
      float a0=As[kk][ty*4+0],a1=As[kk][ty*4+1],a2=As[kk][ty*4+2],a3=As[kk][ty*4+3];
      float b0=Bs[kk][tx*4+0],b1=Bs[kk][tx*4+1],b2=Bs[kk][tx*4+2],b3=Bs[kk][tx*4+3];
      acc[0][0]+=a0*b0; acc[0][1]+=a0*b1; acc[0][2]+=a0*b2; acc[0][3]+=a0*b3;
      acc[1][0]+=a1*b0; acc[1][1]+=a1*b1; acc[1][2]+=a1*b2; acc[1][3]+=a1*b3;
      acc[2][0]+=a2*b0; acc[2][1]+=a2*b1; acc[2][2]+=a2*b2; acc[2][3]+=a2*b3;
      acc[3][0]+=a3*b0; acc[3][1]+=a3*b1; acc[3][2]+=a3*b2; acc[3][3]+=a3*b3;
    }
    __syncthreads();
  }
  int hh = col0 >> 8, bb = row0 >> 11;
  int cv0 = col0 & 255, tl0 = row0 & 2047;
  #pragma unroll
  for(int i=0;i<4;i++){
    #pragma unroll
    for(int j=0;j<4;j++){
      size_t idx = (size_t)(row0+ty*4+i)*N + col0+tx*4+j;
      float val = acc[i][j];
      if(Cf)  Cf[idx]  = val;
      if(Cbf) Cbf[idx] = f2bf(val);
      if(CbfT) CbfT[((size_t)((bb*H_+hh)*256 + cv0+tx*4+j))*T_ + tl0+ty*4+i] = f2bf(val);
    }
  }
}

// ---------------- softmax over 256 (in place), one row per block ----------------
__global__ void softmax256_kernel(float* __restrict__ g){
  int row = blockIdx.x, tid = threadIdx.x;
  float x = g[(size_t)row*256+tid];
  __shared__ float red[256];
  red[tid]=x; __syncthreads();
  for(int s=128;s>0;s>>=1){ if(tid<s) red[tid]=fmaxf(red[tid],red[tid+s]); __syncthreads(); }
  float m = red[0]; __syncthreads();
  float e = expf(x-m);
  red[tid]=e; __syncthreads();
  for(int s=128;s>0;s>>=1){ if(tid<s) red[tid]+=red[tid+s]; __syncthreads(); }
  g[(size_t)row*256+tid] = e/red[0];
}

// ---------------- per-chunk outer product states ----------------
__global__ __launch_bounds__(256) void chunk_outer_kernel(const float* __restrict__ in1f,
    const unsigned short* __restrict__ in1bf,
    const float* __restrict__ g, float* __restrict__ out, int transpose_out){
  int n=blockIdx.x, h=blockIdx.y, b=blockIdx.z;
  int tid=threadIdx.x, t0=n*64;
  __shared__ float g_lds[64][68];
  for(int i=0;i<64;i+=4){
    int rr = i + (tid>>6), cc = tid&63;
    g_lds[rr][cc] = g[((size_t)(b*T_ + t0 + rr))*256 + h*64 + cc];
  }
  __syncthreads();
  float acc[64]={};
  for(int u=0;u<64;u++){
    size_t idx = ((size_t)(b*T_ + t0 + u))*D_ + h*CK_ + tid;
    float a = in1f ? in1f[idx] : bf2f(in1bf[idx]);
    #pragma unroll
    for(int s=0;s<64;s++) acc[s] += a*g_lds[u][s];
  }
  size_t base = (size_t)(b*H_+h)*NC_ + n;
  if(transpose_out){
    #pragma unroll 4
    for(int s=0;s<64;s++) out[(base*64+s)*256 + tid] = acc[s];
  } else {
    #pragma unroll 4
    for(int s=0;s<64;s++) out[(base*256+tid)*64 + s] = acc[s];
  }
}

// ---------------- exclusive prefix over chunks (in place, f32) ----------------
__global__ void chunk_prefix_kernel(float* __restrict__ arr){
  int idx = blockIdx.x*256 + threadIdx.x;
  int bh = idx >> 14, e = idx & 16383;
  float run = 0.f;
  size_t base = (size_t)bh*NC_*16384 + e;
  for(int n=0;n<NC_;n++){
    size_t a = base + (size_t)n*16384;
    float t = arr[a]; arr[a] = run; run += t;
  }
}

// ---------------- exclusive prefix over chunks -> split bf16 hi/lo ----------------
// reads arr (f32, unchanged), writes hi/lo bf16 at the same flat indices.
__global__ void chunk_prefix_split_kernel(const float* __restrict__ arr,
    unsigned short* __restrict__ hi, unsigned short* __restrict__ lo){
  int idx = blockIdx.x*256 + threadIdx.x;
  int bh = idx >> 14, e = idx & 16383;
  float run = 0.f;
  size_t base = (size_t)bh*NC_*16384 + e;
  for(int n=0;n<NC_;n++){
    size_t a = base + (size_t)n*16384;
    float t = arr[a];
    unsigned short hh = f2bf(run);
    hi[a] = hh;
    lo[a] = f2bf(run - bf2f(hh));
    run += t;
  }
}

// ---------------- g (B*T,256) -> GT[bh*NC+n][s][u] split bf16 hi/lo ----------------
__global__ __launch_bounds__(256) void g_transpose_split_kernel(const float* __restrict__ g,
    unsigned short* __restrict__ gthi, unsigned short* __restrict__ gtlo){
  int n=blockIdx.x, h=blockIdx.y, b=blockIdx.z;
  int tid=threadIdx.x, t0=n*64;
  __shared__ float tt[64][65];
  #pragma unroll
  for(int p=0;p<16;p++){
    int u = (tid>>6) + p*4, s = tid&63;
    tt[s][u] = g[((size_t)(b*T_ + t0 + u))*256 + h*64 + s];
  }
  __syncthreads();
  size_t base = ((size_t)(b*H_+h)*NC_ + n)*64;
  #pragma unroll
  for(int p=0;p<16;p++){
    int s = (tid>>6) + p*4, u = tid&63;
    float v = tt[s][u];
    unsigned short hh = f2bf(v);
    gthi[(base+s)*64 + u] = hh;
    gtlo[(base+s)*64 + u] = f2bf(v - bf2f(hh));
  }
}

// ---------------- sc_state via MFMA (split-bf16, fp32-class numerics) ----------------
// sc[t][s] = Q@S1 + tril(Q S^T)@G, per (b,h,chunk). 4 waves, each owns a
// 16-row strip x all 64 cols. B-fragments read straight from global
// (L2-resident, just produced). Only A takes an LDS round-trip.
__global__ __launch_bounds__(256,1) void sc_state_mfma(
    const unsigned short* __restrict__ q_bf,
    const unsigned short* __restrict__ s_bf,
    const unsigned short* __restrict__ S1hi, const unsigned short* __restrict__ S1lo,
    const unsigned short* __restrict__ gthi, const unsigned short* __restrict__ gtlo,
    float* __restrict__ sc_state)
{
  int n=blockIdx.x, h=blockIdx.y, b=blockIdx.z;
  int tid=threadIdx.x, lane=tid&63, w=tid>>6;
  int quad=lane>>4, lq=lane&15;
  int t0=n*64, bh=b*H_+h, strip=w*16;

  __shared__ unsigned short A_hi[64*72];
  __shared__ unsigned short A_lo[64*72];

  // q A-frags for this wave's strip: A[m=lq][k=quad*8+j], 8 k-steps of 32
  bf16x8 qf[8];
  const unsigned short* qrow = q_bf + ((size_t)(b*T_ + t0 + strip + lq))*D_ + h*CK_ + quad*8;
  #pragma unroll
  for(int ks=0;ks<8;ks++) qf[ks] = *(const bf16x8*)(const void*)(qrow + ks*32);

  // ---- stage 1: A = Q S^T (bf16 products, f32 accum — numerics as before) ----
  const unsigned short* sbase = s_bf + ((size_t)(b*T_ + t0))*D_ + h*CK_;
  f32x4 a1[4];
  #pragma unroll
  for(int nf=0;nf<4;nf++) a1[nf] = (f32x4){0.f,0.f,0.f,0.f};
  #pragma unroll
  for(int ks=0;ks<8;ks++){
    #pragma unroll
    for(int nf=0;nf<4;nf++){
      bf16x8 sf = *(const bf16x8*)(const void*)(sbase + (size_t)(nf*16+lq)*D_ + ks*32 + quad*8);
      a1[nf] = __builtin_amdgcn_mfma_f32_16x16x32_bf16(qf[ks], sf, a1[nf], 0,0,0);
    }
  }
  // mask tril, split to hi/lo, store to LDS (row-major [t][u], stride 72)
  #pragma unroll
  for(int nf=0;nf<4;nf++){
    int u = nf*16 + lq;
    #pragma unroll
    for(int i=0;i<4;i++){
      int trow = strip + quad*4 + i;
      float val = (u <= trow) ? a1[nf][i] : 0.f;
      unsigned short hh = f2bf(val);
      A_hi[trow*72 + u] = hh;
      A_lo[trow*72 + u] = f2bf(val - bf2f(hh));
    }
  }
  __syncthreads();

  // A-operand frags: rows strip+lq, k=u consecutive (2 k-steps for K=64)
  bf16x8 afh[2], afl[2];
  #pragma unroll
  for(int ks=0;ks<2;ks++){
    afh[ks] = *(const bf16x8*)(const void*)&A_hi[(strip+lq)*72 + ks*32 + quad*8];
    afl[ks] = *(const bf16x8*)(const void*)&A_lo[(strip+lq)*72 + ks*32 + quad*8];
  }

  // ---- stage 2: acc = Q@(S1hi+S1lo) + Ahi@(Ghi+Glo) + Alo@Ghi ----
  size_t s1base = ((size_t)bh*NC_ + n)*16384;
  size_t gtbase = ((size_t)bh*NC_ + n)*64;
  f32x4 acc2[4];
  #pragma unroll
  for(int nf=0;nf<4;nf++) acc2[nf] = (f32x4){0.f,0.f,0.f,0.f};
  #pragma unroll
  for(int ks=0;ks<8;ks++){
    #pragma unroll
    for(int nf=0;nf<4;nf++){
      size_t off = s1base + (size_t)(nf*16+lq)*256 + ks*32 + quad*8;
      bf16x8 b1 = *(const bf16x8*)(const void*)(S1hi + off);
      acc2[nf] = __builtin_amdgcn_mfma_f32_16x16x32_bf16(qf[ks], b1, acc2[nf], 0,0,0);
      bf16x8 b2 = *(const bf16x8*)(const void*)(S1lo + off);
      acc2[nf] = __builtin_amdgcn_mfma_f32_16x16x32_bf16(qf[ks], b2, acc2[nf], 0,0,0);
    }
  }
  #pragma unroll
  for(int ks=0;ks<2;ks++){
    #pragma unroll
    for(int nf=0;nf<4;nf++){
      size_t off = (gtbase + nf*16+lq)*64 + ks*32 + quad*8;
      bf16x8 gh = *(const bf16x8*)(const void*)(gthi + off);
      bf16x8 gl = *(const bf16x8*)(const void*)(gtlo + off);
      acc2[nf] = __builtin_amdgcn_mfma_f32_16x16x32_bf16(afh[ks], gh, acc2[nf], 0,0,0);
      acc2[nf] = __builtin_amdgcn_mfma_f32_16x16x32_bf16(afh[ks], gl, acc2[nf], 0,0,0);
      acc2[nf] = __builtin_amdgcn_mfma_f32_16x16x32_bf16(afl[ks], gh, acc2[nf], 0,0,0);
    }
  }
  // write out
  #pragma unroll
  for(int nf=0;nf<4;nf++){
    #pragma unroll
    for(int i=0;i<4;i++){
      int trow = strip + quad*4 + i;
      sc_state[((size_t)bh*T_ + t0 + trow)*64 + nf*16+lq] = acc2[nf][i];
    }
  }
}

// ---------------- MFMA fused window attention + joint softmax ----------------
__global__ __launch_bounds__(256,1) void window_attn_mfma(
    const unsigned short* __restrict__ q_bf,
    const unsigned short* __restrict__ k_bf,
    const unsigned short* __restrict__ vt_bf,
    const float* __restrict__ sc_state,
    float* __restrict__ o, float* __restrict__ p_state)
{
  int nt=blockIdx.x, h=blockIdx.y, b=blockIdx.z;
  int tid=threadIdx.x;
  int lane = tid & 63, w = tid >> 6;
  int quad = lane >> 4, lq = lane & 15;
  int sp = w >> 1, np = w & 1;
  int t0 = nt*64, bh = b*H_ + h;
  float slope = exp2f(-2.0f*(float)h);

  __shared__ unsigned short kv_lds[256*72];   // union: K 64x260 (16640) / VT 256x72 (18432)
  __shared__ float S_lds[64*68];
  __shared__ unsigned short P_lds[64*72];
  __shared__ float m_lds[64], l_lds[64], al_lds[64];

  bf16x8 qf[2][8];
  #pragma unroll
  for(int st=0; st<2; st++){
    const unsigned short* qrow = q_bf + ((size_t)(b*T_ + t0 + 32*sp + 16*st + lq))*D_ + h*CK_ + quad*8;
    #pragma unroll
    for(int ks=0; ks<8; ks++)
      qf[st][ks] = *(const bf16x8*)(const void*)(qrow + ks*32);
  }

  int r = tid >> 2, part = tid & 3;
  {
    const float* scrow = sc_state + ((size_t)bh*T_ + t0 + r)*64 + part*16;
    float pm = -1e30f, sv[16];
    #pragma unroll
    for(int i=0;i<16;i++){ sv[i] = scrow[i]; pm = fmaxf(pm, sv[i]); }
    pm = fmaxf(pm, __shfl_xor(pm,1)); pm = fmaxf(pm, __shfl_xor(pm,2));
    float ps = 0.f;
    #pragma unroll
    for(int i=0;i<16;i++) ps += __expf(sv[i]-pm);
    ps += __shfl_xor(ps,1); ps += __shfl_xor(ps,2);
    if(part==0){ m_lds[r]=pm; l_lds[r]=ps; }
  }

  f32x4 o_acc[2][8];
  #pragma unroll
  for(int st=0;st<2;st++)
    #pragma unroll
    for(int nv=0;nv<8;nv++) o_acc[st][nv] = (f32x4){0.f,0.f,0.f,0.f};
  __syncthreads();

  int jt0 = (nt>=8)? nt-8 : 0;
  for(int jt=jt0; jt<=nt; jt++){
    int j0 = jt*64;
    {
      int row = tid>>2, seg = tid&3;
      const unsigned short* src = k_bf + ((size_t)(b*T_ + j0 + row))*D_ + h*CK_ + seg*64;
      unsigned short* dst = kv_lds + row*260 + seg*64;
      #pragma unroll
      for(int i=0;i<8;i++) *(bf16x8*)(void*)(dst + i*8) = *(const bf16x8*)(const void*)(src + i*8);
    }
    __syncthreads();
    f32x4 sacc[2][2];
    #pragma unroll
    for(int st=0;st<2;st++)
      #pragma unroll
      for(int n2=0;n2<2;n2++) sacc[st][n2] = (f32x4){0.f,0.f,0.f,0.f};
    #pragma unroll
    for(int n2=0;n2<2;n2++){
      int n = np*2 + n2;
      #pragma unroll
      for(int ks=0;ks<8;ks++){
        bf16x8 kf = *(const bf16x8*)(const void*)(kv_lds + (n*16+lq)*260 + ks*32 + quad*8);
        sacc[0][n2] = __builtin_amdgcn_mfma_f32_16x16x32_bf16(qf[0][ks], kf, sacc[0][n2], 0,0,0);
        sacc[1][n2] = __builtin_amdgcn_mfma_f32_16x16x32_bf16(qf[1][ks], kf, sacc[1][n2], 0,0,0);
      }
    }
    #pragma unroll
    for(int st=0;st<2;st++){
      #pragma unroll
      for(int n2=0;n2<2;n2++){
        int n = np*2+n2;
        int u = j0 + n*16 + lq;
        #pragma unroll
        for(int i=0;i<4;i++){
          int row = 32*sp + 16*st + quad*4 + i;
          int d = (t0 + row) - u;
          float val = (d>=0 && d<W_) ? sacc[st][n2][i] - slope*(float)d : -1e30f;
          S_lds[row*68 + n*16+lq] = val;
        }
      }
    }
    __syncthreads();
    {
      float s16[16], tm = -1e30f;
      #pragma unroll
      for(int i=0;i<16;i++){ s16[i] = S_lds[r*68 + part*16 + i]; tm = fmaxf(tm, s16[i]); }
      tm = fmaxf(tm, __shfl_xor(tm,1)); tm = fmaxf(tm, __shfl_xor(tm,2));
      float m_old = m_lds[r];
      float m_new = fmaxf(m_old, tm);
      float alpha = __expf(m_old - m_new);
      float ts = 0.f;
      union { unsigned short u[16]; bf16x8 v[2]; } pk;
      #pragma unroll
      for(int i=0;i<16;i++){ float p = __expf(s16[i]-m_new); ts += p; pk.u[i] = f2bf(p); }
      ts += __shfl_xor(ts,1); ts += __shfl_xor(ts,2);
      *(bf16x8*)(void*)&P_lds[r*72 + part*16]     = pk.v[0];
      *(bf16x8*)(void*)&P_lds[r*72 + part*16 + 8] = pk.v[1];
      if(part==0){ m_lds[r] = m_new; l_lds[r] = l_lds[r]*alpha + ts; al_lds[r] = alpha; }
      #pragma unroll
      for(int pass=0; pass<4; pass++){
        int cv = (tid>>2) + 64*pass, useg = (tid&3)*16;
        const unsigned short* src = vt_bf + ((size_t)(bh*256 + cv))*T_ + j0 + useg;
        unsigned short* dst = kv_lds + cv*72 + useg;
        *(bf16x8*)(void*)(dst)   = *(const bf16x8*)(const void*)(src);
        *(bf16x8*)(void*)(dst+8) = *(const bf16x8*)(const void*)(src+8);
      }
    }
    __syncthreads();
    #pragma unroll
    for(int st=0;st<2;st++){
      #pragma unroll
      for(int i=0;i<4;i++){
        float al = al_lds[32*sp+16*st+quad*4+i];
        #pragma unroll
        for(int nv=0;nv<8;nv++) o_acc[st][nv][i] *= al;
      }
    }
    bf16x8 pa[2][2];
    #pragma unroll
    for(int st=0;st<2;st++)
      #pragma unroll
      for(int k2=0;k2<2;k2++)
        pa[st][k2] = *(const bf16x8*)(const void*)&P_lds[(32*sp+16*st+lq)*72 + k2*32 + quad*8];
    #pragma unroll
    for(int nv=0;nv<8;nv++){
      int cvt = np*8 + nv;
      #pragma unroll
      for(int k2=0;k2<2;k2++){
        bf16x8 vb = *(const bf16x8*)(const void*)(kv_lds + (cvt*16+lq)*72 + k2*32 + quad*8);
        o_acc[0][nv] = __builtin_amdgcn_mfma_f32_16x16x32_bf16(pa[0][k2], vb, o_acc[0][nv], 0,0,0);
        o_acc[1][nv] = __builtin_amdgcn_mfma_f32_16x16x32_bf16(pa[1][k2], vb, o_acc[1][nv], 0,0,0);
      }
    }
    __syncthreads();
  }
  #pragma unroll
  for(int st=0;st<2;st++){
    #pragma unroll
    for(int i=0;i<4;i++){
      int row = 32*sp+16*st+quad*4+i;
      float rl = 1.0f / l_lds[row];
      #pragma unroll
      for(int nv=0;nv<8;nv++){
        int cv = (np*8+nv)*16 + lq;
        o[((size_t)bh*T_ + t0 + row)*256 + cv] = o_acc[st][nv][i] * rl;
      }
    }
  }
  {
    float mf = m_lds[r], rlf = 1.0f / l_lds[r];
    const float* scrow = sc_state + ((size_t)bh*T_ + t0 + r)*64 + part*16;
    float* pr = p_state + ((size_t)bh*T_ + t0 + r)*64 + part*16;
    #pragma unroll
    for(int i=0;i<16;i++) pr[i] = __expf(scrow[i]-mf)*rlf;
  }
}

// ---------------- o += p_state @ SG + tril(p_state·g^T) @ v ----------------
__global__ __launch_bounds__(256) void o_state_kernel(const float* __restrict__ p_state,
    const float* __restrict__ g,
    const float* __restrict__ v, const float* __restrict__ SG, float* __restrict__ o){
  int n=blockIdx.x, h=blockIdx.y, b=blockIdx.z;
  int tid=threadIdx.x, t0=n*64;
  __shared__ float p_lds[64*69];
  __shared__ float g_lds[64*69];
  __shared__ float M_lds[64*65];
  for(int i=0;i<16;i++){
    int rr = (tid>>6) + i*4, cc = tid&63;
    p_lds[rr*69+cc] = p_state[((size_t)(b*H_+h)*T_ + t0+rr)*64 + cc];
    g_lds[rr*69+cc] = g[((size_t)(b*T_+t0+rr))*256 + h*64 + cc];
  }
  __syncthreads();
  int u = tid & 63;
  #pragma unroll 1
  for(int kk=0;kk<16;kk++){
    int t = (tid>>6) + kk*4;
    float dot=0.f;
    #pragma unroll
    for(int s=0;s<64;s++) dot += p_lds[t*69+s]*g_lds[u*69+s];
    M_lds[t*65+u] = (u<=t)? dot : 0.f;
  }
  __syncthreads();
  float acc[64];
  #pragma unroll
  for(int t=0;t<64;t++) acc[t]=0.f;
  size_t sgbase = ((size_t)(b*H_+h)*NC_+n)*16384;
  for(int s=0;s<64;s++){
    float gsc = SG[sgbase + s*256 + tid];
    #pragma unroll
    for(int t=0;t<64;t++) acc[t] += p_lds[t*69+s]*gsc;
  }
  for(int uu=0;uu<64;uu++){
    float vv = v[((size_t)(b*T_+t0+uu))*D_ + h*CK_ + tid];
    #pragma unroll
    for(int t=0;t<64;t++) acc[t] += M_lds[t*65+uu]*vv;
  }
  #pragma unroll 4
  for(int t=0;t<64;t++){
    size_t oi = ((size_t)(b*H_+h)*T_ + t0+t)*256 + tid;
    o[oi] += acc[t];
  }
}

// ---------------- swish + rmsnorm, gather heads -> (B*T, D) ----------------
__global__ void swish_rms_kernel(const float* __restrict__ o, const float* __restrict__ w,
                                 float* __restrict__ o2){
  int bt=blockIdx.x, tid=threadIdx.x;
  int b = bt >> 11, t = bt & 2047;
  float y[4]; float ss=0.f;
  #pragma unroll
  for(int hh=0;hh<4;hh++){
    float x = o[((size_t)(b*H_+hh)*T_ + t)*256 + tid];
    float yy = x / (1.f + expf(-x));
    y[hh]=yy; ss += yy*yy;
  }
  __shared__ float red[256];
  red[tid]=ss; __syncthreads();
  for(int s2=128;s2>0;s2>>=1){ if(tid<s2) red[tid]+=red[tid+s2]; __syncthreads(); }
  float r = rsqrtf(red[0]/1024.f + 1e-5f);
  #pragma unroll
  for(int hh=0;hh<4;hh++)
    o2[(size_t)bt*1024 + hh*256 + tid] = y[hh]*r*w[hh*256+tid];
}

extern "C" void kernel_launch(void* const* d_in, const int* in_sizes, int n_in,
                              void* d_out, int out_size, void* d_ws, size_t ws_size,
                              hipStream_t stream){
  const float* hidden = (const float*)d_in[0];
  const float* w_norm = (const float*)d_in[1];
  const float* Wq = (const float*)d_in[2];
  const float* Wk = (const float*)d_in[3];
  const float* Wv = (const float*)d_in[4];
  const float* Ws = (const float*)d_in[5];
  const float* Wg = (const float*)d_in[6];
  const float* Wo = (const float*)d_in[7];
  float* out = (float*)d_out;

  char* p = (char*)d_ws;
  auto alloc = [&](size_t bytes)->void*{ void* r = (void*)p; p += (bytes + 255) & ~(size_t)255; return r; };
  float* h   = (float*)alloc(16777216);           // (4096,1024) f32
  float* v   = (float*)alloc(16777216);           // (4096,1024) f32
  float* g   = (float*)alloc(4194304);            // (4096,256)  f32
  float* P1  = (float*)alloc(16777216);           // (8,32,64,256) f32 chunk states; later aliased by vt_bf
  float* P2  = (float*)alloc(16777216);           // (8,32,64,256) f32 -> excl prefix; S1hi/S1lo alias until chunk_outer(P2)
  float* sc  = (float*)alloc(4194304);            // (8,2048,64)
  float* ps  = (float*)alloc(4194304);            // (8,2048,64)
  float* o   = (float*)alloc(16777216);           // (8,2048,256); GThi/GTlo alias until window_attn
  unsigned short* q_bf = (unsigned short*)alloc(8388608);
  unsigned short* k_bf = (unsigned short*)alloc(8388608);
  unsigned short* s_bf = (unsigned short*)alloc(8388608);
  float* o2 = h;                       // h dead after v-gemm; reuse for post-swish activations
  unsigned short* vt_bf = (unsigned short*)P1;  // P1 dead after prefix_split; reuse for V^T bf16 (8MB)
  // S1 split-bf16 prefix state: aliases P2 (first written by chunk_outer(P2), AFTER sc_state consumed S1)
  unsigned short* S1hi = (unsigned short*)P2;
  unsigned short* S1lo = (unsigned short*)((char*)P2 + 8388608);
  // GT split-bf16 transposed gates: aliases o (first written by window_attn, AFTER sc_state)
  unsigned short* GThi = (unsigned short*)o;
  unsigned short* GTlo = (unsigned short*)((char*)o + 2097152);

  rmsnorm_kernel<<<4096,256,0,stream>>>(hidden, w_norm, h);
  dim3 g64(16,64), ggrid(4,64);
  gemm_nt<<<g64,256,0,stream>>>(h, Wq, nullptr, q_bf, nullptr, 4096,1024,1024);
  gemm_nt<<<g64,256,0,stream>>>(h, Wk, nullptr, k_bf, nullptr, 4096,1024,1024);
  gemm_nt<<<g64,256,0,stream>>>(h, Ws, nullptr, s_bf, nullptr, 4096,1024,1024);
  gemm_nt<<<ggrid,256,0,stream>>>(h, Wg, g, nullptr, nullptr, 4096,256,1024);
  softmax256_kernel<<<4096,256,0,stream>>>(g);
  dim3 gc(32,4,2);
  g_transpose_split_kernel<<<gc,256,0,stream>>>(g, GThi, GTlo);
  chunk_outer_kernel<<<gc,256,0,stream>>>(nullptr, s_bf, g, P1, 1);   // transposed: [s][c]
  chunk_prefix_split_kernel<<<512,256,0,stream>>>(P1, S1hi, S1lo);
  sc_state_mfma<<<gc,256,0,stream>>>(q_bf, s_bf, S1hi, S1lo, GThi, GTlo, sc);
  // P1 consumed; now safe to overwrite with vt_bf
  gemm_nt<<<g64,256,0,stream>>>(h, Wv, v, nullptr, vt_bf, 4096,1024,1024);
  chunk_outer_kernel<<<gc,256,0,stream>>>(v, nullptr, g, P2, 1);
  chunk_prefix_kernel<<<512,256,0,stream>>>(P2);
  window_attn_mfma<<<gc,256,0,stream>>>(q_bf, k_bf, vt_bf, sc, o, ps);
  o_state_kernel<<<gc,256,0,stream>>>(ps, g, v, P2, o);
  swish_rms_kernel<<<4096,256,0,stream>>>(o, w_norm, o2);
  gemm_nt<<<g64,256,0,stream>>>(o2, Wo, out, nullptr, nullptr, 4096,1024,1024);
}

// Round 3
// 559.841 us; speedup vs baseline: 2.1170x; 1.8715x over previous
//
#include <hip/hip_runtime.h>
#include <stdint.h>

#define B_  2
#define T_  2048
#define D_  1024
#define H_  4
#define S_  64
#define W_  512
#define CK_ 256
#define NC_ 32      // T_/64 chunks

typedef __attribute__((ext_vector_type(8))) short bf16x8;
typedef __attribute__((ext_vector_type(4))) float f32x4;
typedef __attribute__((ext_vector_type(4))) unsigned short u16x4;

__device__ __forceinline__ float bf2f(unsigned short u){ return __uint_as_float(((unsigned int)u)<<16); }
__device__ __forceinline__ unsigned short f2bf(float f){
  unsigned int u = __float_as_uint(f);
  u += 0x7fffu + ((u>>16)&1u);
  return (unsigned short)(u>>16);
}
__device__ __forceinline__ void split2(float y, unsigned short& hi, unsigned short& lo){
  hi = f2bf(y);
  lo = f2bf(y - bf2f(hi));
}

// ---------------- RMSNorm: x(B*T,D) -> split bf16 hi/lo ----------------
__global__ void rmsnorm_split_kernel(const float* __restrict__ x, const float* __restrict__ w,
                                     unsigned short* __restrict__ ohi, unsigned short* __restrict__ olo){
  int row = blockIdx.x, tid = threadIdx.x;
  const float* xr = x + (size_t)row*D_;
  float v0=xr[tid], v1=xr[tid+256], v2=xr[tid+512], v3=xr[tid+768];
  __shared__ float red[256];
  red[tid] = v0*v0+v1*v1+v2*v2+v3*v3;
  __syncthreads();
  for(int s=128;s>0;s>>=1){ if(tid<s) red[tid]+=red[tid+s]; __syncthreads(); }
  float r = rsqrtf(red[0]/(float)D_ + 1e-5f);
  size_t base = (size_t)row*D_;
  float y0=v0*r*w[tid], y1=v1*r*w[tid+256], y2=v2*r*w[tid+512], y3=v3*r*w[tid+768];
  unsigned short hh, ll;
  split2(y0,hh,ll); ohi[base+tid]=hh;     olo[base+tid]=ll;
  split2(y1,hh,ll); ohi[base+tid+256]=hh; olo[base+tid+256]=ll;
  split2(y2,hh,ll); ohi[base+tid+512]=hh; olo[base+tid+512]=ll;
  split2(y3,hh,ll); ohi[base+tid+768]=hh; olo[base+tid+768]=ll;
}

// ---------------- weight concat + split: rows [Wq;Wk;Ws;Wv;Wg;Wo] ----------------
__global__ void wsplit_kernel(const float* __restrict__ Wq, const float* __restrict__ Wk,
                              const float* __restrict__ Ws, const float* __restrict__ Wv,
                              const float* __restrict__ Wg, const float* __restrict__ Wo,
                              unsigned short* __restrict__ whi, unsigned short* __restrict__ wlo){
  int row = blockIdx.x, tid = threadIdx.x;
  const float* src;
  if(row < 1024)      src = Wq + (size_t)row*1024;
  else if(row < 2048) src = Wk + (size_t)(row-1024)*1024;
  else if(row < 3072) src = Ws + (size_t)(row-2048)*1024;
  else if(row < 4096) src = Wv + (size_t)(row-3072)*1024;
  else if(row < 4352) src = Wg + (size_t)(row-4096)*1024;
  else                src = Wo + (size_t)(row-4352)*1024;
  f32x4 vv = *(const f32x4*)(src + tid*4);
  u16x4 hh, ll;
  #pragma unroll
  for(int j=0;j<4;j++){ unsigned short a,b; split2(vv[j],a,b); hh[j]=a; ll[j]=b; }
  *(u16x4*)(whi + (size_t)row*1024 + tid*4) = hh;
  *(u16x4*)(wlo + (size_t)row*1024 + tid*4) = ll;
}

// ---------------- split-bf16 MFMA GEMM: C[M,4352] = A[4096,1024] * Wcat^T ----------------
// mode 0: fused epilogue -> qks(bf16), v(f32)+vt(bf16 transposed), g(f32)
// mode 1: Cf[row*1024+col] = val (Wo projection)
// 128x128 tile, BK=32, 4 waves (2x2), each wave 64x64 = 4x4 frags of 16x16x32.
// 3-term split product: Ah*Bh + Ah*Bl + Al*Bh (lo*lo dropped, ~2^-18 rel).
__global__ __launch_bounds__(256,2) void gemm_bf16s(
    const unsigned short* __restrict__ Ahi, const unsigned short* __restrict__ Alo,
    const unsigned short* __restrict__ Whi, const unsigned short* __restrict__ Wlo,
    unsigned short* __restrict__ qks, float* __restrict__ vout,
    unsigned short* __restrict__ vt, float* __restrict__ gout,
    float* __restrict__ Cf, int mode)
{
  __shared__ unsigned short Ah_s[128*40];
  __shared__ unsigned short Al_s[128*40];
  __shared__ unsigned short Bh_s[128*40];
  __shared__ unsigned short Bl_s[128*40];
  int tid = threadIdx.x;
  int lane = tid & 63, w = tid >> 6;
  int quad = lane >> 4, lq = lane & 15;
  int wr = w >> 1, wc = w & 1;
  int row0 = blockIdx.y*128, col0 = blockIdx.x*128;
  int sr = tid >> 2, scc = (tid & 3)*8;

  const unsigned short* pa0 = Ahi + (size_t)(row0+sr)*1024 + scc;
  const unsigned short* pal = Alo + (size_t)(row0+sr)*1024 + scc;
  const unsigned short* pb0 = Whi + (size_t)(col0+sr)*1024 + scc;
  const unsigned short* pbl = Wlo + (size_t)(col0+sr)*1024 + scc;

  f32x4 acc[4][4];
  #pragma unroll
  for(int i=0;i<4;i++)
    #pragma unroll
    for(int j=0;j<4;j++) acc[i][j] = (f32x4){0.f,0.f,0.f,0.f};

  for(int kt=0; kt<1024; kt+=32){
    bf16x8 a0  = *(const bf16x8*)(const void*)(pa0 + kt);
    bf16x8 a1  = *(const bf16x8*)(const void*)(pa0 + 64*1024 + kt);
    bf16x8 al0 = *(const bf16x8*)(const void*)(pal + kt);
    bf16x8 al1 = *(const bf16x8*)(const void*)(pal + 64*1024 + kt);
    bf16x8 b0  = *(const bf16x8*)(const void*)(pb0 + kt);
    bf16x8 b1  = *(const bf16x8*)(const void*)(pb0 + 64*1024 + kt);
    bf16x8 bl0 = *(const bf16x8*)(const void*)(pbl + kt);
    bf16x8 bl1 = *(const bf16x8*)(const void*)(pbl + 64*1024 + kt);
    __syncthreads();
    *(bf16x8*)(void*)(Ah_s + sr*40 + scc)      = a0;
    *(bf16x8*)(void*)(Ah_s + (sr+64)*40 + scc) = a1;
    *(bf16x8*)(void*)(Al_s + sr*40 + scc)      = al0;
    *(bf16x8*)(void*)(Al_s + (sr+64)*40 + scc) = al1;
    *(bf16x8*)(void*)(Bh_s + sr*40 + scc)      = b0;
    *(bf16x8*)(void*)(Bh_s + (sr+64)*40 + scc) = b1;
    *(bf16x8*)(void*)(Bl_s + sr*40 + scc)      = bl0;
    *(bf16x8*)(void*)(Bl_s + (sr+64)*40 + scc) = bl1;
    __syncthreads();
    bf16x8 afh[4], afl[4], bfh[4], bfl[4];
    #pragma unroll
    for(int i=0;i<4;i++){
      afh[i] = *(const bf16x8*)(const void*)(Ah_s + (wr*64+i*16+lq)*40 + quad*8);
      afl[i] = *(const bf16x8*)(const void*)(Al_s + (wr*64+i*16+lq)*40 + quad*8);
      bfh[i] = *(const bf16x8*)(const void*)(Bh_s + (wc*64+i*16+lq)*40 + quad*8);
      bfl[i] = *(const bf16x8*)(const void*)(Bl_s + (wc*64+i*16+lq)*40 + quad*8);
    }
    #pragma unroll
    for(int mi=0;mi<4;mi++)
      #pragma unroll
      for(int ni=0;ni<4;ni++){
        acc[mi][ni] = __builtin_amdgcn_mfma_f32_16x16x32_bf16(afh[mi], bfh[ni], acc[mi][ni], 0,0,0);
        acc[mi][ni] = __builtin_amdgcn_mfma_f32_16x16x32_bf16(afh[mi], bfl[ni], acc[mi][ni], 0,0,0);
        acc[mi][ni] = __builtin_amdgcn_mfma_f32_16x16x32_bf16(afl[mi], bfh[ni], acc[mi][ni], 0,0,0);
      }
  }

  int rbase = row0 + wr*64, cbase = col0 + wc*64;
  if(mode == 1){
    #pragma unroll
    for(int mi=0;mi<4;mi++)
      #pragma unroll
      for(int ni=0;ni<4;ni++)
        #pragma unroll
        for(int i=0;i<4;i++)
          Cf[(size_t)(rbase+mi*16+quad*4+i)*1024 + cbase+ni*16+lq] = acc[mi][ni][i];
  } else if(col0 < 3072){
    unsigned short* dst = qks + (size_t)(col0>>10)*4194304;
    #pragma unroll
    for(int mi=0;mi<4;mi++)
      #pragma unroll
      for(int ni=0;ni<4;ni++)
        #pragma unroll
        for(int i=0;i<4;i++){
          int rr = rbase+mi*16+quad*4+i, cc = (cbase+ni*16+lq) & 1023;
          dst[(size_t)rr*1024 + cc] = f2bf(acc[mi][ni][i]);
        }
  } else if(col0 < 4096){
    #pragma unroll
    for(int mi=0;mi<4;mi++)
      #pragma unroll
      for(int ni=0;ni<4;ni++)
        #pragma unroll
        for(int i=0;i<4;i++){
          int rr = rbase+mi*16+quad*4+i, cl = (cbase+ni*16+lq) & 1023;
          float val = acc[mi][ni][i];
          vout[(size_t)rr*1024 + cl] = val;
          int hh = cl>>8, cv = cl&255, bb = rr>>11, tt = rr&2047;
          vt[((size_t)((bb*H_+hh)*256 + cv))*T_ + tt] = f2bf(val);
        }
  } else {
    #pragma unroll
    for(int mi=0;mi<4;mi++)
      #pragma unroll
      for(int ni=0;ni<4;ni++)
        #pragma unroll
        for(int i=0;i<4;i++){
          int rr = rbase+mi*16+quad*4+i, cl = cbase+ni*16+lq - 4096;
          gout[(size_t)rr*256 + cl] = acc[mi][ni][i];
        }
  }
}

// ---------------- softmax over 256 (in place), one row per block ----------------
__global__ void softmax256_kernel(float* __restrict__ g){
  int row = blockIdx.x, tid = threadIdx.x;
  float x = g[(size_t)row*256+tid];
  __shared__ float red[256];
  red[tid]=x; __syncthreads();
  for(int s=128;s>0;s>>=1){ if(tid<s) red[tid]=fmaxf(red[tid],red[tid+s]); __syncthreads(); }
  float m = red[0]; __syncthreads();
  float e = expf(x-m);
  red[tid]=e; __syncthreads();
  for(int s=128;s>0;s>>=1){ if(tid<s) red[tid]+=red[tid+s]; __syncthreads(); }
  g[(size_t)row*256+tid] = e/red[0];
}

// ---------------- per-chunk outer product states ----------------
__global__ __launch_bounds__(256) void chunk_outer_kernel(const float* __restrict__ in1f,
    const unsigned short* __restrict__ in1bf,
    const float* __restrict__ g, float* __restrict__ out, int transpose_out){
  int n=blockIdx.x, h=blockIdx.y, b=blockIdx.z;
  int tid=threadIdx.x, t0=n*64;
  __shared__ float g_lds[64][68];
  for(int i=0;i<64;i+=4){
    int rr = i + (tid>>6), cc = tid&63;
    g_lds[rr][cc] = g[((size_t)(b*T_ + t0 + rr))*256 + h*64 + cc];
  }
  __syncthreads();
  float acc[64]={};
  for(int u=0;u<64;u++){
    size_t idx = ((size_t)(b*T_ + t0 + u))*D_ + h*CK_ + tid;
    float a = in1f ? in1f[idx] : bf2f(in1bf[idx]);
    #pragma unroll
    for(int s=0;s<64;s++) acc[s] += a*g_lds[u][s];
  }
  size_t base = (size_t)(b*H_+h)*NC_ + n;
  if(transpose_out){
    #pragma unroll 4
    for(int s=0;s<64;s++) out[(base*64+s)*256 + tid] = acc[s];
  } else {
    #pragma unroll 4
    for(int s=0;s<64;s++) out[(base*256+tid)*64 + s] = acc[s];
  }
}

// ---------------- exclusive prefix over chunks (in place, f32) ----------------
__global__ void chunk_prefix_kernel(float* __restrict__ arr){
  int idx = blockIdx.x*256 + threadIdx.x;
  int bh = idx >> 14, e = idx & 16383;
  float run = 0.f;
  size_t base = (size_t)bh*NC_*16384 + e;
  for(int n=0;n<NC_;n++){
    size_t a = base + (size_t)n*16384;
    float t = arr[a]; arr[a] = run; run += t;
  }
}

// ---------------- exclusive prefix over chunks -> split bf16 hi/lo ----------------
__global__ void chunk_prefix_split_kernel(const float* __restrict__ arr,
    unsigned short* __restrict__ hi, unsigned short* __restrict__ lo){
  int idx = blockIdx.x*256 + threadIdx.x;
  int bh = idx >> 14, e = idx & 16383;
  float run = 0.f;
  size_t base = (size_t)bh*NC_*16384 + e;
  for(int n=0;n<NC_;n++){
    size_t a = base + (size_t)n*16384;
    float t = arr[a];
    unsigned short hh, ll;
    split2(run, hh, ll);
    hi[a] = hh; lo[a] = ll;
    run += t;
  }
}

// ---------------- g (B*T,256) -> GT[bh*NC+n][s][u] split bf16 hi/lo ----------------
__global__ __launch_bounds__(256) void g_transpose_split_kernel(const float* __restrict__ g,
    unsigned short* __restrict__ gthi, unsigned short* __restrict__ gtlo){
  int n=blockIdx.x, h=blockIdx.y, b=blockIdx.z;
  int tid=threadIdx.x, t0=n*64;
  __shared__ float tt[64][65];
  #pragma unroll
  for(int p=0;p<16;p++){
    int u = (tid>>6) + p*4, s = tid&63;
    tt[s][u] = g[((size_t)(b*T_ + t0 + u))*256 + h*64 + s];
  }
  __syncthreads();
  size_t base = ((size_t)(b*H_+h)*NC_ + n)*64;
  #pragma unroll
  for(int p=0;p<16;p++){
    int s = (tid>>6) + p*4, u = tid&63;
    unsigned short hh, ll;
    split2(tt[s][u], hh, ll);
    gthi[(base+s)*64 + u] = hh;
    gtlo[(base+s)*64 + u] = ll;
  }
}

// ---------------- sc_state via MFMA (split-bf16, fp32-class numerics) ----------------
__global__ __launch_bounds__(256,1) void sc_state_mfma(
    const unsigned short* __restrict__ q_bf,
    const unsigned short* __restrict__ s_bf,
    const unsigned short* __restrict__ S1hi, const unsigned short* __restrict__ S1lo,
    const unsigned short* __restrict__ gthi, const unsigned short* __restrict__ gtlo,
    float* __restrict__ sc_state)
{
  int n=blockIdx.x, h=blockIdx.y, b=blockIdx.z;
  int tid=threadIdx.x, lane=tid&63, w=tid>>6;
  int quad=lane>>4, lq=lane&15;
  int t0=n*64, bh=b*H_+h, strip=w*16;

  __shared__ unsigned short A_hi[64*72];
  __shared__ unsigned short A_lo[64*72];

  bf16x8 qf[8];
  const unsigned short* qrow = q_bf + ((size_t)(b*T_ + t0 + strip + lq))*D_ + h*CK_ + quad*8;
  #pragma unroll
  for(int ks=0;ks<8;ks++) qf[ks] = *(const bf16x8*)(const void*)(qrow + ks*32);

  const unsigned short* sbase = s_bf + ((size_t)(b*T_ + t0))*D_ + h*CK_;
  f32x4 a1[4];
  #pragma unroll
  for(int nf=0;nf<4;nf++) a1[nf] = (f32x4){0.f,0.f,0.f,0.f};
  #pragma unroll
  for(int ks=0;ks<8;ks++){
    #pragma unroll
    for(int nf=0;nf<4;nf++){
      bf16x8 sf = *(const bf16x8*)(const void*)(sbase + (size_t)(nf*16+lq)*D_ + ks*32 + quad*8);
      a1[nf] = __builtin_amdgcn_mfma_f32_16x16x32_bf16(qf[ks], sf, a1[nf], 0,0,0);
    }
  }
  #pragma unroll
  for(int nf=0;nf<4;nf++){
    int u = nf*16 + lq;
    #pragma unroll
    for(int i=0;i<4;i++){
      int trow = strip + quad*4 + i;
      float val = (u <= trow) ? a1[nf][i] : 0.f;
      unsigned short hh, ll;
      split2(val, hh, ll);
      A_hi[trow*72 + u] = hh;
      A_lo[trow*72 + u] = ll;
    }
  }
  __syncthreads();

  bf16x8 afh[2], afl[2];
  #pragma unroll
  for(int ks=0;ks<2;ks++){
    afh[ks] = *(const bf16x8*)(const void*)&A_hi[(strip+lq)*72 + ks*32 + quad*8];
    afl[ks] = *(const bf16x8*)(const void*)&A_lo[(strip+lq)*72 + ks*32 + quad*8];
  }

  size_t s1base = ((size_t)bh*NC_ + n)*16384;
  size_t gtbase = ((size_t)bh*NC_ + n)*64;
  f32x4 acc2[4];
  #pragma unroll
  for(int nf=0;nf<4;nf++) acc2[nf] = (f32x4){0.f,0.f,0.f,0.f};
  #pragma unroll
  for(int ks=0;ks<8;ks++){
    #pragma unroll
    for(int nf=0;nf<4;nf++){
      size_t off = s1base + (size_t)(nf*16+lq)*256 + ks*32 + quad*8;
      bf16x8 b1 = *(const bf16x8*)(const void*)(S1hi + off);
      acc2[nf] = __builtin_amdgcn_mfma_f32_16x16x32_bf16(qf[ks], b1, acc2[nf], 0,0,0);
      bf16x8 b2 = *(const bf16x8*)(const void*)(S1lo + off);
      acc2[nf] = __builtin_amdgcn_mfma_f32_16x16x32_bf16(qf[ks], b2, acc2[nf], 0,0,0);
    }
  }
  #pragma unroll
  for(int ks=0;ks<2;ks++){
    #pragma unroll
    for(int nf=0;nf<4;nf++){
      size_t off = (gtbase + nf*16+lq)*64 + ks*32 + quad*8;
      bf16x8 gh = *(const bf16x8*)(const void*)(gthi + off);
      bf16x8 gl = *(const bf16x8*)(const void*)(gtlo + off);
      acc2[nf] = __builtin_amdgcn_mfma_f32_16x16x32_bf16(afh[ks], gh, acc2[nf], 0,0,0);
      acc2[nf] = __builtin_amdgcn_mfma_f32_16x16x32_bf16(afh[ks], gl, acc2[nf], 0,0,0);
      acc2[nf] = __builtin_amdgcn_mfma_f32_16x16x32_bf16(afl[ks], gh, acc2[nf], 0,0,0);
    }
  }
  #pragma unroll
  for(int nf=0;nf<4;nf++){
    #pragma unroll
    for(int i=0;i<4;i++){
      int trow = strip + quad*4 + i;
      sc_state[((size_t)bh*T_ + t0 + trow)*64 + nf*16+lq] = acc2[nf][i];
    }
  }
}

// ---------------- MFMA fused window attention + joint softmax ----------------
__global__ __launch_bounds__(256,1) void window_attn_mfma(
    const unsigned short* __restrict__ q_bf,
    const unsigned short* __restrict__ k_bf,
    const unsigned short* __restrict__ vt_bf,
    const float* __restrict__ sc_state,
    float* __restrict__ o, float* __restrict__ p_state)
{
  int nt=blockIdx.x, h=blockIdx.y, b=blockIdx.z;
  int tid=threadIdx.x;
  int lane = tid & 63, w = tid >> 6;
  int quad = lane >> 4, lq = lane & 15;
  int sp = w >> 1, np = w & 1;
  int t0 = nt*64, bh = b*H_ + h;
  float slope = exp2f(-2.0f*(float)h);

  __shared__ unsigned short kv_lds[256*72];
  __shared__ float S_lds[64*68];
  __shared__ unsigned short P_lds[64*72];
  __shared__ float m_lds[64], l_lds[64], al_lds[64];

  bf16x8 qf[2][8];
  #pragma unroll
  for(int st=0; st<2; st++){
    const unsigned short* qrow = q_bf + ((size_t)(b*T_ + t0 + 32*sp + 16*st + lq))*D_ + h*CK_ + quad*8;
    #pragma unroll
    for(int ks=0; ks<8; ks++)
      qf[st][ks] = *(const bf16x8*)(const void*)(qrow + ks*32);
  }

  int r = tid >> 2, part = tid & 3;
  {
    const float* scrow = sc_state + ((size_t)bh*T_ + t0 + r)*64 + part*16;
    float pm = -1e30f, sv[16];
    #pragma unroll
    for(int i=0;i<16;i++){ sv[i] = scrow[i]; pm = fmaxf(pm, sv[i]); }
    pm = fmaxf(pm, __shfl_xor(pm,1)); pm = fmaxf(pm, __shfl_xor(pm,2));
    float ps = 0.f;
    #pragma unroll
    for(int i=0;i<16;i++) ps += __expf(sv[i]-pm);
    ps += __shfl_xor(ps,1); ps += __shfl_xor(ps,2);
    if(part==0){ m_lds[r]=pm; l_lds[r]=ps; }
  }

  f32x4 o_acc[2][8];
  #pragma unroll
  for(int st=0;st<2;st++)
    #pragma unroll
    for(int nv=0;nv<8;nv++) o_acc[st][nv] = (f32x4){0.f,0.f,0.f,0.f};
  __syncthreads();

  int jt0 = (nt>=8)? nt-8 : 0;
  for(int jt=jt0; jt<=nt; jt++){
    int j0 = jt*64;
    {
      int row = tid>>2, seg = tid&3;
      const unsigned short* src = k_bf + ((size_t)(b*T_ + j0 + row))*D_ + h*CK_ + seg*64;
      unsigned short* dst = kv_lds + row*260 + seg*64;
      #pragma unroll
      for(int i=0;i<8;i++) *(bf16x8*)(void*)(dst + i*8) = *(const bf16x8*)(const void*)(src + i*8);
    }
    __syncthreads();
    f32x4 sacc[2][2];
    #pragma unroll
    for(int st=0;st<2;st++)
      #pragma unroll
      for(int n2=0;n2<2;n2++) sacc[st][n2] = (f32x4){0.f,0.f,0.f,0.f};
    #pragma unroll
    for(int n2=0;n2<2;n2++){
      int n = np*2 + n2;
      #pragma unroll
      for(int ks=0;ks<8;ks++){
        bf16x8 kf = *(const bf16x8*)(const void*)(kv_lds + (n*16+lq)*260 + ks*32 + quad*8);
        sacc[0][n2] = __builtin_amdgcn_mfma_f32_16x16x32_bf16(qf[0][ks], kf, sacc[0][n2], 0,0,0);
        sacc[1][n2] = __builtin_amdgcn_mfma_f32_16x16x32_bf16(qf[1][ks], kf, sacc[1][n2], 0,0,0);
      }
    }
    #pragma unroll
    for(int st=0;st<2;st++){
      #pragma unroll
      for(int n2=0;n2<2;n2++){
        int n = np*2+n2;
        int u = j0 + n*16 + lq;
        #pragma unroll
        for(int i=0;i<4;i++){
          int row = 32*sp + 16*st + quad*4 + i;
          int d = (t0 + row) - u;
          float val = (d>=0 && d<W_) ? sacc[st][n2][i] - slope*(float)d : -1e30f;
          S_lds[row*68 + n*16+lq] = val;
        }
      }
    }
    __syncthreads();
    {
      float s16[16], tm = -1e30f;
      #pragma unroll
      for(int i=0;i<16;i++){ s16[i] = S_lds[r*68 + part*16 + i]; tm = fmaxf(tm, s16[i]); }
      tm = fmaxf(tm, __shfl_xor(tm,1)); tm = fmaxf(tm, __shfl_xor(tm,2));
      float m_old = m_lds[r];
      float m_new = fmaxf(m_old, tm);
      float alpha = __expf(m_old - m_new);
      float ts = 0.f;
      union { unsigned short u[16]; bf16x8 v[2]; } pk;
      #pragma unroll
      for(int i=0;i<16;i++){ float p = __expf(s16[i]-m_new); ts += p; pk.u[i] = f2bf(p); }
      ts += __shfl_xor(ts,1); ts += __shfl_xor(ts,2);
      *(bf16x8*)(void*)&P_lds[r*72 + part*16]     = pk.v[0];
      *(bf16x8*)(void*)&P_lds[r*72 + part*16 + 8] = pk.v[1];
      if(part==0){ m_lds[r] = m_new; l_lds[r] = l_lds[r]*alpha + ts; al_lds[r] = alpha; }
      #pragma unroll
      for(int pass=0; pass<4; pass++){
        int cv = (tid>>2) + 64*pass, useg = (tid&3)*16;
        const unsigned short* src = vt_bf + ((size_t)(bh*256 + cv))*T_ + j0 + useg;
        unsigned short* dst = kv_lds + cv*72 + useg;
        *(bf16x8*)(void*)(dst)   = *(const bf16x8*)(const void*)(src);
        *(bf16x8*)(void*)(dst+8) = *(const bf16x8*)(const void*)(src+8);
      }
    }
    __syncthreads();
    #pragma unroll
    for(int st=0;st<2;st++){
      #pragma unroll
      for(int i=0;i<4;i++){
        float al = al_lds[32*sp+16*st+quad*4+i];
        #pragma unroll
        for(int nv=0;nv<8;nv++) o_acc[st][nv][i] *= al;
      }
    }
    bf16x8 pa[2][2];
    #pragma unroll
    for(int st=0;st<2;st++)
      #pragma unroll
      for(int k2=0;k2<2;k2++)
        pa[st][k2] = *(const bf16x8*)(const void*)&P_lds[(32*sp+16*st+lq)*72 + k2*32 + quad*8];
    #pragma unroll
    for(int nv=0;nv<8;nv++){
      int cvt = np*8 + nv;
      #pragma unroll
      for(int k2=0;k2<2;k2++){
        bf16x8 vb = *(const bf16x8*)(const void*)(kv_lds + (cvt*16+lq)*72 + k2*32 + quad*8);
        o_acc[0][nv] = __builtin_amdgcn_mfma_f32_16x16x32_bf16(pa[0][k2], vb, o_acc[0][nv], 0,0,0);
        o_acc[1][nv] = __builtin_amdgcn_mfma_f32_16x16x32_bf16(pa[1][k2], vb, o_acc[1][nv], 0,0,0);
      }
    }
    __syncthreads();
  }
  #pragma unroll
  for(int st=0;st<2;st++){
    #pragma unroll
    for(int i=0;i<4;i++){
      int row = 32*sp+16*st+quad*4+i;
      float rl = 1.0f / l_lds[row];
      #pragma unroll
      for(int nv=0;nv<8;nv++){
        int cv = (np*8+nv)*16 + lq;
        o[((size_t)bh*T_ + t0 + row)*256 + cv] = o_acc[st][nv][i] * rl;
      }
    }
  }
  {
    float mf = m_lds[r], rlf = 1.0f / l_lds[r];
    const float* scrow = sc_state + ((size_t)bh*T_ + t0 + r)*64 + part*16;
    float* pr = p_state + ((size_t)bh*T_ + t0 + r)*64 + part*16;
    #pragma unroll
    for(int i=0;i<16;i++) pr[i] = __expf(scrow[i]-mf)*rlf;
  }
}

// ---------------- o += p_state @ SG + tril(p_state·g^T) @ v ----------------
__global__ __launch_bounds__(256) void o_state_kernel(const float* __restrict__ p_state,
    const float* __restrict__ g,
    const float* __restrict__ v, const float* __restrict__ SG, float* __restrict__ o){
  int n=blockIdx.x, h=blockIdx.y, b=blockIdx.z;
  int tid=threadIdx.x, t0=n*64;
  __shared__ float p_lds[64*69];
  __shared__ float g_lds[64*69];
  __shared__ float M_lds[64*65];
  for(int i=0;i<16;i++){
    int rr = (tid>>6) + i*4, cc = tid&63;
    p_lds[rr*69+cc] = p_state[((size_t)(b*H_+h)*T_ + t0+rr)*64 + cc];
    g_lds[rr*69+cc] = g[((size_t)(b*T_+t0+rr))*256 + h*64 + cc];
  }
  __syncthreads();
  int u = tid & 63;
  #pragma unroll 1
  for(int kk=0;kk<16;kk++){
    int t = (tid>>6) + kk*4;
    float dot=0.f;
    #pragma unroll
    for(int s=0;s<64;s++) dot += p_lds[t*69+s]*g_lds[u*69+s];
    M_lds[t*65+u] = (u<=t)? dot : 0.f;
  }
  __syncthreads();
  float acc[64];
  #pragma unroll
  for(int t=0;t<64;t++) acc[t]=0.f;
  size_t sgbase = ((size_t)(b*H_+h)*NC_+n)*16384;
  for(int s=0;s<64;s++){
    float gsc = SG[sgbase + s*256 + tid];
    #pragma unroll
    for(int t=0;t<64;t++) acc[t] += p_lds[t*69+s]*gsc;
  }
  for(int uu=0;uu<64;uu++){
    float vv = v[((size_t)(b*T_+t0+uu))*D_ + h*CK_ + tid];
    #pragma unroll
    for(int t=0;t<64;t++) acc[t] += M_lds[t*65+uu]*vv;
  }
  #pragma unroll 4
  for(int t=0;t<64;t++){
    size_t oi = ((size_t)(b*H_+h)*T_ + t0+t)*256 + tid;
    o[oi] += acc[t];
  }
}

// ---------------- swish + rmsnorm, gather heads -> split bf16 hi/lo ----------------
__global__ void swish_rms_split_kernel(const float* __restrict__ o, const float* __restrict__ w,
                                       unsigned short* __restrict__ ohi, unsigned short* __restrict__ olo){
  int bt=blockIdx.x, tid=threadIdx.x;
  int b = bt >> 11, t = bt & 2047;
  float y[4]; float ss=0.f;
  #pragma unroll
  for(int hh=0;hh<4;hh++){
    float x = o[((size_t)(b*H_+hh)*T_ + t)*256 + tid];
    float yy = x / (1.f + expf(-x));
    y[hh]=yy; ss += yy*yy;
  }
  __shared__ float red[256];
  red[tid]=ss; __syncthreads();
  for(int s2=128;s2>0;s2>>=1){ if(tid<s2) red[tid]+=red[tid+s2]; __syncthreads(); }
  float r = rsqrtf(red[0]/1024.f + 1e-5f);
  #pragma unroll
  for(int hh=0;hh<4;hh++){
    unsigned short a,bq;
    split2(y[hh]*r*w[hh*256+tid], a, bq);
    ohi[(size_t)bt*1024 + hh*256 + tid] = a;
    olo[(size_t)bt*1024 + hh*256 + tid] = bq;
  }
}

extern "C" void kernel_launch(void* const* d_in, const int* in_sizes, int n_in,
                              void* d_out, int out_size, void* d_ws, size_t ws_size,
                              hipStream_t stream){
  const float* hidden = (const float*)d_in[0];
  const float* w_norm = (const float*)d_in[1];
  const float* Wq = (const float*)d_in[2];
  const float* Wk = (const float*)d_in[3];
  const float* Wv = (const float*)d_in[4];
  const float* Ws = (const float*)d_in[5];
  const float* Wg = (const float*)d_in[6];
  const float* Wo = (const float*)d_in[7];
  float* out = (float*)d_out;

  char* p = (char*)d_ws;
  auto alloc = [&](size_t bytes)->void*{ void* r = (void*)p; p += (bytes + 255) & ~(size_t)255; return r; };
  unsigned short* h_hi = (unsigned short*)alloc(8388608);   // (4096,1024) bf16; reused for o2_hi
  unsigned short* h_lo = (unsigned short*)alloc(8388608);   //               ; reused for o2_lo
  unsigned short* Wc_hi = (unsigned short*)alloc(11010048); // (5376,1024) bf16 [Wq;Wk;Ws;Wv;Wg;Wo]
  unsigned short* Wc_lo = (unsigned short*)alloc(11010048);
  float* v   = (float*)alloc(16777216);                     // (4096,1024) f32
  float* g   = (float*)alloc(4194304);                      // (4096,256)  f32
  float* P1  = (float*)alloc(16777216);                     // chunk states; o aliases after prefix_split
  float* P2  = (float*)alloc(16777216);                     // S1hi/S1lo alias until chunk_outer(v)
  float* sc  = (float*)alloc(4194304);                      // (8,2048,64)
  float* ps  = (float*)alloc(4194304);                      // p_state; GThi/GTlo alias until window_attn
  unsigned short* qks = (unsigned short*)alloc(25165824);   // q|k|s bf16, 3x(4096,1024)
  unsigned short* vt  = (unsigned short*)alloc(8388608);    // V^T bf16 (8,256,2048)

  unsigned short* q_bf = qks;
  unsigned short* k_bf = qks + 4194304;
  unsigned short* s_bf = qks + 8388608;
  float* o = P1;                                   // P1 dead after chunk_prefix_split
  unsigned short* S1hi = (unsigned short*)P2;      // consumed by sc_state before chunk_outer(v) writes P2
  unsigned short* S1lo = S1hi + 4194304;
  unsigned short* GThi = (unsigned short*)ps;      // consumed by sc_state before window_attn writes ps
  unsigned short* GTlo = GThi + 1048576;

  rmsnorm_split_kernel<<<4096,256,0,stream>>>(hidden, w_norm, h_hi, h_lo);
  wsplit_kernel<<<5376,256,0,stream>>>(Wq, Wk, Ws, Wv, Wg, Wo, Wc_hi, Wc_lo);
  gemm_bf16s<<<dim3(34,32),256,0,stream>>>(h_hi, h_lo, Wc_hi, Wc_lo,
                                           qks, v, vt, g, nullptr, 0);
  softmax256_kernel<<<4096,256,0,stream>>>(g);
  dim3 gc(32,4,2);
  g_transpose_split_kernel<<<gc,256,0,stream>>>(g, GThi, GTlo);
  chunk_outer_kernel<<<gc,256,0,stream>>>(nullptr, s_bf, g, P1, 1);   // transposed: [s][c]
  chunk_prefix_split_kernel<<<512,256,0,stream>>>(P1, S1hi, S1lo);
  sc_state_mfma<<<gc,256,0,stream>>>(q_bf, s_bf, S1hi, S1lo, GThi, GTlo, sc);
  chunk_outer_kernel<<<gc,256,0,stream>>>(v, nullptr, g, P2, 1);
  chunk_prefix_kernel<<<512,256,0,stream>>>(P2);
  window_attn_mfma<<<gc,256,0,stream>>>(q_bf, k_bf, vt, sc, o, ps);
  o_state_kernel<<<gc,256,0,stream>>>(ps, g, v, P2, o);
  swish_rms_split_kernel<<<4096,256,0,stream>>>(o, w_norm, h_hi, h_lo);
  gemm_bf16s<<<dim3(8,32),256,0,stream>>>(h_hi, h_lo, Wc_hi + (size_t)4352*1024, Wc_lo + (size_t)4352*1024,
                                          nullptr, nullptr, nullptr, nullptr, out, 1);
}